// Round 1
// baseline (336.803 us; speedup 1.0000x reference)
//
#include <hip/hip_runtime.h>

#define PPB   256      // points per block in the main kernel (must be multiple of 2)
#define NZ    8
#define INC   64
#define OUTC  128
#define NB    4
#define HH    256
#define WWD   256
#define HWD   (HH * WWD)

// ---------------- binning: histogram ----------------
__global__ void hist_kernel(const int* __restrict__ z_idx, int* __restrict__ counts, int n) {
    __shared__ int lc[NZ];
    int t = threadIdx.x;
    if (t < NZ) lc[t] = 0;
    __syncthreads();
    int i = blockIdx.x * blockDim.x + t;
    if (i < n) {
        int z = z_idx[i]; z = z < 0 ? 0 : (z > NZ - 1 ? NZ - 1 : z);
        atomicAdd(&lc[z], 1);
    }
    __syncthreads();
    if (t < NZ && lc[t] > 0) atomicAdd(&counts[t], lc[t]);
}

// ---------------- binning: padded prefix ----------------
__global__ void prefix_kernel(const int* __restrict__ counts, int* __restrict__ pstart,
                              int* __restrict__ cursors) {
    if (threadIdx.x == 0 && blockIdx.x == 0) {
        int off = 0;
        for (int z = 0; z < NZ; ++z) {
            pstart[z] = off;
            off += ((counts[z] + PPB - 1) / PPB) * PPB;   // pad each bin to PPB multiple
            cursors[z] = 0;
        }
        pstart[NZ] = off;   // padded total
    }
}

// ---------------- binning: scatter point ids ----------------
__global__ void scatter_kernel(const int* __restrict__ z_idx, const int* __restrict__ pstart,
                               int* __restrict__ cursors, int* __restrict__ bins, int n) {
    __shared__ int lc[NZ];
    __shared__ int lbase[NZ];
    int t = threadIdx.x;
    if (t < NZ) lc[t] = 0;
    __syncthreads();
    int i = blockIdx.x * blockDim.x + t;
    int z = 0, rank = 0;
    bool valid = (i < n);
    if (valid) {
        z = z_idx[i]; z = z < 0 ? 0 : (z > NZ - 1 ? NZ - 1 : z);
        rank = atomicAdd(&lc[z], 1);
    }
    __syncthreads();
    if (t < NZ) lbase[t] = (lc[t] > 0) ? atomicAdd(&cursors[t], lc[t]) : 0;
    __syncthreads();
    if (valid) bins[pstart[z] + lbase[z] + rank] = i;
}

// ---------------- main: per-point matmul + coalesced scatter-add (BHWC ws) ----------------
// One block = one z (guaranteed by padded bins). Thread c holds W[z][:,c] in 64 VGPRs.
__global__ __launch_bounds__(256) void spmm_kernel(
        const float* __restrict__ features, const float* __restrict__ kw,
        const float* __restrict__ bias,
        const int* __restrict__ batch_idx, const int* __restrict__ d0_idx,
        const int* __restrict__ d1_idx,
        const int* __restrict__ pstart, const int* __restrict__ bins,
        float* __restrict__ bev) {
    int start = blockIdx.x * PPB;
    int total = pstart[NZ];
    if (start >= total) return;
    int z = 0;
#pragma unroll
    for (int zz = 1; zz < NZ; ++zz)
        if (start >= pstart[zz]) z = zz;

    int c   = threadIdx.x & (OUTC - 1);   // 0..127
    int sub = threadIdx.x >> 7;           // 0..1

    // cache weight column W[z][:,c] in registers (read once per block, coalesced)
    float w[INC];
    const float* wp = kw + (size_t)z * INC * OUTC + c;
#pragma unroll
    for (int i = 0; i < INC; ++i) w[i] = wp[(size_t)i * OUTC];
    float bc = bias[c];

    for (int p = sub; p < PPB; p += 2) {
        int nid = bins[start + p];
        if (nid < 0) continue;                       // padding entry (wave-uniform)
        nid = __builtin_amdgcn_readfirstlane(nid);
        const float4* fp = (const float4*)(features + (size_t)nid * INC);
        float a0 = bc, a1 = 0.f, a2 = 0.f, a3 = 0.f;
#pragma unroll
        for (int i = 0; i < INC / 4; ++i) {
            float4 f = fp[i];                        // wave-uniform broadcast load
            a0 += f.x * w[4 * i + 0];
            a1 += f.y * w[4 * i + 1];
            a2 += f.z * w[4 * i + 2];
            a3 += f.w * w[4 * i + 3];
        }
        float acc = (a0 + a1) + (a2 + a3);
        int bi = __builtin_amdgcn_readfirstlane(batch_idx[nid]);
        int h  = __builtin_amdgcn_readfirstlane(d0_idx[nid]);
        int wd = __builtin_amdgcn_readfirstlane(d1_idx[nid]);
        size_t flat = (size_t)bi * HWD + (size_t)h * WWD + wd;
        unsafeAtomicAdd(&bev[flat * OUTC + c], acc);   // 512B contiguous per point
    }
}

// ---------------- transpose BHWC -> BCHW (writes every output element) ----------------
__global__ __launch_bounds__(256) void transpose_kernel(const float* __restrict__ bev,
                                                        float* __restrict__ out) {
    __shared__ float tile[32][33];
    int tx = threadIdx.x;           // 0..31
    int ty = threadIdx.y;           // 0..7
    int pTile = blockIdx.x * 32;    // position base within HW
    int cTile = blockIdx.y * 32;    // channel base
    int b = blockIdx.z;
    const float* src = bev + (size_t)b * HWD * OUTC;
#pragma unroll
    for (int k = 0; k < 4; ++k) {
        int pos = pTile + ty + k * 8;
        tile[ty + k * 8][tx] = src[(size_t)pos * OUTC + cTile + tx];
    }
    __syncthreads();
    float* dst = out + (size_t)b * OUTC * HWD;
#pragma unroll
    for (int k = 0; k < 4; ++k) {
        int ch = cTile + ty + k * 8;
        dst[(size_t)ch * HWD + pTile + tx] = tile[tx][ty + k * 8];
    }
}

// ---------------- fallback (ws too small): direct scattered atomics into BCHW ----------------
__global__ __launch_bounds__(256) void naive_kernel(
        const float* __restrict__ features, const float* __restrict__ kw,
        const float* __restrict__ bias,
        const int* __restrict__ bidx, const int* __restrict__ d0,
        const int* __restrict__ d1, const int* __restrict__ zi,
        float* __restrict__ out, int n) {
    long long gid = (long long)blockIdx.x * blockDim.x + threadIdx.x;
    int pid = (int)(gid >> 7);
    int c   = (int)(gid & (OUTC - 1));
    if (pid >= n) return;
    int z = zi[pid]; z = z < 0 ? 0 : (z > NZ - 1 ? NZ - 1 : z);
    const float4* fp = (const float4*)(features + (size_t)pid * INC);
    const float* wp = kw + (size_t)z * INC * OUTC + c;
    float a0 = bias[c], a1 = 0.f, a2 = 0.f, a3 = 0.f;
#pragma unroll
    for (int i = 0; i < INC / 4; ++i) {
        float4 f = fp[i];
        a0 += f.x * wp[(size_t)(4 * i + 0) * OUTC];
        a1 += f.y * wp[(size_t)(4 * i + 1) * OUTC];
        a2 += f.z * wp[(size_t)(4 * i + 2) * OUTC];
        a3 += f.w * wp[(size_t)(4 * i + 3) * OUTC];
    }
    float acc = (a0 + a1) + (a2 + a3);
    size_t oidx = ((size_t)bidx[pid] * OUTC + c) * HWD + (size_t)d0[pid] * WWD + d1[pid];
    unsafeAtomicAdd(&out[oidx], acc);
}

extern "C" void kernel_launch(void* const* d_in, const int* in_sizes, int n_in,
                              void* d_out, int out_size, void* d_ws, size_t ws_size,
                              hipStream_t stream) {
    const float* features = (const float*)d_in[0];
    const float* kw       = (const float*)d_in[1];
    const float* bias     = (const float*)d_in[2];
    const int* batch_idx  = (const int*)d_in[3];
    const int* d0_idx     = (const int*)d_in[4];
    const int* d1_idx     = (const int*)d_in[5];
    const int* z_idx      = (const int*)d_in[6];
    float* out = (float*)d_out;
    int n = in_sizes[0] / INC;   // number of points

    size_t bevBytes = (size_t)NB * HWD * OUTC * sizeof(float);   // 128 MiB
    size_t metaOff  = bevBytes;
    size_t binsOff  = bevBytes + 128;
    size_t binsElems = (size_t)n + (size_t)NZ * PPB;
    size_t need = binsOff + binsElems * sizeof(int);

    if (ws_size >= need) {
        char* ws = (char*)d_ws;
        float* bev   = (float*)ws;
        int* counts  = (int*)(ws + metaOff);     // 8 ints
        int* cursors = counts + 8;               // 8 ints
        int* pstart  = counts + 16;              // 9 ints
        int* bins    = (int*)(ws + binsOff);

        hipMemsetAsync(bev, 0, bevBytes, stream);
        hipMemsetAsync(counts, 0, 128, stream);                  // counts+cursors+pstart
        hipMemsetAsync(bins, 0xFF, binsElems * sizeof(int), stream);  // -1 padding

        int gb = (n + 255) / 256;
        hist_kernel<<<gb, 256, 0, stream>>>(z_idx, counts, n);
        prefix_kernel<<<1, 64, 0, stream>>>(counts, pstart, cursors);
        scatter_kernel<<<gb, 256, 0, stream>>>(z_idx, pstart, cursors, bins, n);

        int nblk = (int)((binsElems + PPB - 1) / PPB) + 1;       // covers padded total
        spmm_kernel<<<nblk, 256, 0, stream>>>(features, kw, bias, batch_idx, d0_idx,
                                              d1_idx, pstart, bins, bev);

        dim3 tg(HWD / 32, OUTC / 32, NB), tb(32, 8);
        transpose_kernel<<<tg, tb, 0, stream>>>(bev, out);
    } else {
        hipMemsetAsync(out, 0, (size_t)out_size * sizeof(float), stream);
        long long threads = (long long)n * OUTC;
        int gb = (int)((threads + 255) / 256);
        naive_kernel<<<gb, 256, 0, stream>>>(features, kw, bias, batch_idx, d0_idx,
                                             d1_idx, z_idx, out, n);
    }
}

// Round 2
// 330.544 us; speedup vs baseline: 1.0189x; 1.0189x over previous
//
#include <hip/hip_runtime.h>

#define PPB   128      // points per block in the main kernel (multiple of 8)
#define NZ    8
#define INC   64
#define OUTC  128
#define NB    4
#define HH    256
#define WWD   256
#define HWD   (HH * WWD)

// ---------------- binning: histogram ----------------
__global__ void hist_kernel(const int* __restrict__ z_idx, int* __restrict__ counts, int n) {
    __shared__ int lc[NZ];
    int t = threadIdx.x;
    if (t < NZ) lc[t] = 0;
    __syncthreads();
    int i = blockIdx.x * blockDim.x + t;
    if (i < n) {
        int z = z_idx[i]; z = z < 0 ? 0 : (z > NZ - 1 ? NZ - 1 : z);
        atomicAdd(&lc[z], 1);
    }
    __syncthreads();
    if (t < NZ && lc[t] > 0) atomicAdd(&counts[t], lc[t]);
}

// ---------------- binning: padded prefix ----------------
__global__ void prefix_kernel(const int* __restrict__ counts, int* __restrict__ pstart,
                              int* __restrict__ cursors) {
    if (threadIdx.x == 0 && blockIdx.x == 0) {
        int off = 0;
        for (int z = 0; z < NZ; ++z) {
            pstart[z] = off;
            off += ((counts[z] + PPB - 1) / PPB) * PPB;   // pad each bin to PPB multiple
            cursors[z] = 0;
        }
        pstart[NZ] = off;   // padded total
    }
}

// ---------------- binning: scatter point ids ----------------
__global__ void scatter_kernel(const int* __restrict__ z_idx, const int* __restrict__ pstart,
                               int* __restrict__ cursors, int* __restrict__ bins, int n) {
    __shared__ int lc[NZ];
    __shared__ int lbase[NZ];
    int t = threadIdx.x;
    if (t < NZ) lc[t] = 0;
    __syncthreads();
    int i = blockIdx.x * blockDim.x + t;
    int z = 0, rank = 0;
    bool valid = (i < n);
    if (valid) {
        z = z_idx[i]; z = z < 0 ? 0 : (z > NZ - 1 ? NZ - 1 : z);
        rank = atomicAdd(&lc[z], 1);
    }
    __syncthreads();
    if (t < NZ) lbase[t] = (lc[t] > 0) ? atomicAdd(&cursors[t], lc[t]) : 0;
    __syncthreads();
    if (valid) bins[pstart[z] + lbase[z] + rank] = i;
}

// ---------------- main: per-point matmul + coalesced scatter-add (BHWC ws) ----------------
// One block = one z (guaranteed by padded bins). Thread c holds W[z][:,c] in 64 VGPRs
// (pinned via asm barrier so the compiler can't sink the loads into the point loop).
__global__ __launch_bounds__(256) void spmm_kernel(
        const float* __restrict__ features, const float* __restrict__ kw,
        const float* __restrict__ bias,
        const int* __restrict__ batch_idx, const int* __restrict__ d0_idx,
        const int* __restrict__ d1_idx,
        const int* __restrict__ pstart, const int* __restrict__ bins,
        float* __restrict__ bev) {
    int start = blockIdx.x * PPB;
    int total = pstart[NZ];
    if (start >= total) return;
    int z = 0;
#pragma unroll
    for (int zz = 1; zz < NZ; ++zz)
        if (start >= pstart[zz]) z = zz;

    int c   = threadIdx.x & (OUTC - 1);   // 0..127
    int sub = threadIdx.x >> 7;           // 0..1

    // cache weight column W[z][:,c] in registers (read once per block, coalesced)
    float w[INC];
    const float* wp = kw + (size_t)z * INC * OUTC + c;
#pragma unroll
    for (int i = 0; i < INC; ++i) w[i] = wp[(size_t)i * OUTC];
    // pin in VGPRs: volatile asm can't be sunk, so loads stay hoisted
#pragma unroll
    for (int i = 0; i < INC; ++i) asm volatile("" : "+v"(w[i]));
    float bc = bias[c];

    int base = start + sub * (PPB / 2);
    for (int p0 = 0; p0 < PPB / 2; p0 += 4) {
        int raw[4];
#pragma unroll
        for (int u = 0; u < 4; ++u) raw[u] = bins[base + p0 + u];

        float acc[4];
        size_t cbase[4];
#pragma unroll
        for (int u = 0; u < 4; ++u) {
            int id = raw[u] < 0 ? 0 : raw[u];            // padding -> dummy point 0
            id = __builtin_amdgcn_readfirstlane(id);
            const float4* fp = (const float4*)(features + (size_t)id * INC);
            float a0 = 0.f, a1 = 0.f, a2 = 0.f, a3 = 0.f;
#pragma unroll
            for (int i = 0; i < INC / 4; ++i) {
                float4 f = fp[i];                        // wave-uniform broadcast load
                a0 += f.x * w[4 * i + 0];
                a1 += f.y * w[4 * i + 1];
                a2 += f.z * w[4 * i + 2];
                a3 += f.w * w[4 * i + 3];
            }
            acc[u] = raw[u] < 0 ? 0.f : ((a0 + a1) + (a2 + a3) + bc);  // pad adds 0.0
            int bi = __builtin_amdgcn_readfirstlane(batch_idx[id]);
            int h  = __builtin_amdgcn_readfirstlane(d0_idx[id]);
            int wd = __builtin_amdgcn_readfirstlane(d1_idx[id]);
            cbase[u] = ((size_t)bi * HWD + (size_t)h * WWD + wd) * OUTC;
        }
#pragma unroll
        for (int u = 0; u < 4; ++u)
            unsafeAtomicAdd(&bev[cbase[u] + c], acc[u]);   // 512B contiguous per point
    }
}

// ---------------- transpose BHWC -> BCHW (writes every output element) ----------------
__global__ __launch_bounds__(256) void transpose_kernel(const float* __restrict__ bev,
                                                        float* __restrict__ out) {
    __shared__ float tile[32][33];
    int tx = threadIdx.x;           // 0..31
    int ty = threadIdx.y;           // 0..7
    int pTile = blockIdx.x * 32;    // position base within HW
    int cTile = blockIdx.y * 32;    // channel base
    int b = blockIdx.z;
    const float* src = bev + (size_t)b * HWD * OUTC;
#pragma unroll
    for (int k = 0; k < 4; ++k) {
        int pos = pTile + ty + k * 8;
        tile[ty + k * 8][tx] = src[(size_t)pos * OUTC + cTile + tx];
    }
    __syncthreads();
    float* dst = out + (size_t)b * OUTC * HWD;
#pragma unroll
    for (int k = 0; k < 4; ++k) {
        int ch = cTile + ty + k * 8;
        dst[(size_t)ch * HWD + pTile + tx] = tile[tx][ty + k * 8];
    }
}

// ---------------- fallback (ws too small): direct scattered atomics into BCHW ----------------
__global__ __launch_bounds__(256) void naive_kernel(
        const float* __restrict__ features, const float* __restrict__ kw,
        const float* __restrict__ bias,
        const int* __restrict__ bidx, const int* __restrict__ d0,
        const int* __restrict__ d1, const int* __restrict__ zi,
        float* __restrict__ out, int n) {
    long long gid = (long long)blockIdx.x * blockDim.x + threadIdx.x;
    int pid = (int)(gid >> 7);
    int c   = (int)(gid & (OUTC - 1));
    if (pid >= n) return;
    int z = zi[pid]; z = z < 0 ? 0 : (z > NZ - 1 ? NZ - 1 : z);
    const float4* fp = (const float4*)(features + (size_t)pid * INC);
    const float* wp = kw + (size_t)z * INC * OUTC + c;
    float a0 = bias[c], a1 = 0.f, a2 = 0.f, a3 = 0.f;
#pragma unroll
    for (int i = 0; i < INC / 4; ++i) {
        float4 f = fp[i];
        a0 += f.x * wp[(size_t)(4 * i + 0) * OUTC];
        a1 += f.y * wp[(size_t)(4 * i + 1) * OUTC];
        a2 += f.z * wp[(size_t)(4 * i + 2) * OUTC];
        a3 += f.w * wp[(size_t)(4 * i + 3) * OUTC];
    }
    float acc = (a0 + a1) + (a2 + a3);
    size_t oidx = ((size_t)bidx[pid] * OUTC + c) * HWD + (size_t)d0[pid] * WWD + d1[pid];
    unsafeAtomicAdd(&out[oidx], acc);
}

extern "C" void kernel_launch(void* const* d_in, const int* in_sizes, int n_in,
                              void* d_out, int out_size, void* d_ws, size_t ws_size,
                              hipStream_t stream) {
    const float* features = (const float*)d_in[0];
    const float* kw       = (const float*)d_in[1];
    const float* bias     = (const float*)d_in[2];
    const int* batch_idx  = (const int*)d_in[3];
    const int* d0_idx     = (const int*)d_in[4];
    const int* d1_idx     = (const int*)d_in[5];
    const int* z_idx      = (const int*)d_in[6];
    float* out = (float*)d_out;
    int n = in_sizes[0] / INC;   // number of points

    size_t bevBytes = (size_t)NB * HWD * OUTC * sizeof(float);   // 128 MiB
    size_t metaOff  = bevBytes;
    size_t binsOff  = bevBytes + 128;
    size_t binsElems = (size_t)n + (size_t)NZ * PPB;
    size_t need = binsOff + binsElems * sizeof(int);

    if (ws_size >= need) {
        char* ws = (char*)d_ws;
        float* bev   = (float*)ws;
        int* counts  = (int*)(ws + metaOff);     // 8 ints
        int* cursors = counts + 8;               // 8 ints
        int* pstart  = counts + 16;              // 9 ints
        int* bins    = (int*)(ws + binsOff);

        hipMemsetAsync(bev, 0, bevBytes, stream);
        hipMemsetAsync(counts, 0, 128, stream);                  // counts+cursors+pstart
        hipMemsetAsync(bins, 0xFF, binsElems * sizeof(int), stream);  // -1 padding

        int gb = (n + 255) / 256;
        hist_kernel<<<gb, 256, 0, stream>>>(z_idx, counts, n);
        prefix_kernel<<<1, 64, 0, stream>>>(counts, pstart, cursors);
        scatter_kernel<<<gb, 256, 0, stream>>>(z_idx, pstart, cursors, bins, n);

        int nblk = (int)((binsElems + PPB - 1) / PPB) + 1;       // covers padded total
        spmm_kernel<<<nblk, 256, 0, stream>>>(features, kw, bias, batch_idx, d0_idx,
                                              d1_idx, pstart, bins, bev);

        dim3 tg(HWD / 32, OUTC / 32, NB), tb(32, 8);
        transpose_kernel<<<tg, tb, 0, stream>>>(bev, out);
    } else {
        hipMemsetAsync(out, 0, (size_t)out_size * sizeof(float), stream);
        long long threads = (long long)n * OUTC;
        int gb = (int)((threads + 255) / 256);
        naive_kernel<<<gb, 256, 0, stream>>>(features, kw, bias, batch_idx, d0_idx,
                                             d1_idx, z_idx, out, n);
    }
}